// Round 12
// baseline (128.250 us; speedup 1.0000x reference)
//
#include <hip/hip_runtime.h>

#define TT 200
#define NN 512
#define DD 4
#define HH 64
#define LL 32
#define SB 16                // sequences per block (fills MFMA dim)
#define BPB (NN / SB)        // 32 blocks per batch
#define KP 72                // ushort pitch per h row (144B = 9*16B)
#define LOG2E 1.44269504088896340736f

typedef short bf16x8 __attribute__((ext_vector_type(8)));
typedef float f32x4 __attribute__((ext_vector_type(4)));

union U8 { unsigned short s[8]; unsigned u[4]; bf16x8 v; };

// f32 -> (hi, lo) bf16 limbs by truncation
__device__ __forceinline__ void split2(float x, unsigned short& hi, unsigned short& lo) {
    unsigned u = __float_as_uint(x);
    hi = (unsigned short)(u >> 16);
    float lf = x - __uint_as_float(u & 0xffff0000u);
    lo = (unsigned short)(__float_as_uint(lf) >> 16);
}

__global__ __launch_bounds__(512, 1)
void gru_traj_kernel(const float* __restrict__ xg,    // (B,T,N,D)
                     const float* __restrict__ W_ih,  // (192,4)
                     const float* __restrict__ W_hh,  // (192,64)
                     const float* __restrict__ b_ih,  // (192,)
                     const float* __restrict__ b_hh,  // (192,)
                     const float* __restrict__ W_enc, // (32,64)
                     const float* __restrict__ b_enc, // (32,)
                     float* __restrict__ out)         // (B,N,32)
{
    __shared__ __align__(16) unsigned short hhi[2][SB][KP];   // h hi-limbs (dbuf)
    __shared__ __align__(16) unsigned short hlo[2][SB][KP];   // h lo-limbs
    __shared__ __align__(16) float hsf[SB][HH + 4];           // f32 h for epilogue

    const int tid = threadIdx.x;
    const int bid = blockIdx.x;
    const int b   = bid >> 5;                // bid / BPB
    const int n0  = (bid & (BPB - 1)) * SB;

    const int w  = tid >> 6;     // wave 0..7
    const int wq = w & 3;        // unit-group 16wq..16wq+15 (C tile rows)
    const int wg = w >> 2;       // row-half: gates for C rows {2wg, 2wg+1}
    const int l  = tid & 63;
    const int lr = l & 15;       // A-row / B-col (seq) / C-col (seq)
    const int lg = l >> 4;       // k-group (A/B) and C row-group
    const int u0 = 16 * wq + lg * 4;   // first of 4 C rows this lane's acc holds
    const int ub = u0 + 2 * wg;        // first of 2 owned units (gate phase)

    const float sc[3] = { LOG2E, LOG2E, 2.0f * LOG2E };

    // ---- A statics: W_hh hi-limbs (identical in paired waves wq==wq') ----
    bf16x8 awh[3][2];
    #pragma unroll
    for (int i = 0; i < 3; ++i) {
        const int g = i * 64 + 16 * wq + lr;
        #pragma unroll
        for (int kc = 0; kc < 2; ++kc) {
            const float* p = W_hh + g * HH + kc * 32 + lg * 8;
            U8 uh;
            #pragma unroll
            for (int j = 0; j < 8; ++j) {
                unsigned short hi, lo;
                split2(p[j] * sc[i], hi, lo);
                uh.s[j] = hi; (void)lo;
            }
            awh[i][kc] = uh.v;
        }
    }
    // ---- per-lane gate constants for the 2 owned units (g = i*64 + ub + k) ----
    float wihc[3][2][4], cbrz[2][2], cbx[2], cbh[2];
    #pragma unroll
    for (int i = 0; i < 3; ++i) {
        #pragma unroll
        for (int k = 0; k < 2; ++k) {
            const int g = i * 64 + ub + k;
            #pragma unroll
            for (int d = 0; d < 4; ++d) wihc[i][k][d] = W_ih[g * DD + d] * sc[i];
            if (i < 2) cbrz[i][k] = (b_ih[g] + b_hh[g]) * sc[i];
            else       { cbx[k] = b_ih[g] * sc[2]; cbh[k] = b_hh[g] * sc[2]; }
        }
    }

    // ---- init: zero h limb buffers (h0 = 0) ----
    for (int idx = tid; idx < 2 * SB * KP / 2; idx += 512) {
        reinterpret_cast<unsigned*>(hhi)[idx] = 0u;
        reinterpret_cast<unsigned*>(hlo)[idx] = 0u;
    }
    float hreg[2] = {0.f, 0.f};   // h[s = lr][ub + k]

    // ---- x_0 into registers (lane's seq = n0 + lr) ----
    float4 xc = *reinterpret_cast<const float4*>(
        xg + ((size_t)(b * TT) * NN + n0 + lr) * DD);
    __syncthreads();

    #pragma unroll 2
    for (int t = 0; t < TT; ++t) {
        const int cur = t & 1, nxt = cur ^ 1;
        const int tn  = (t + 1 < TT) ? t + 1 : t;

        // prefetch x_{t+1}
        float4 xn = *reinterpret_cast<const float4*>(
            xg + ((size_t)(b * TT + tn) * NN + n0 + lr) * DD);

        // ---- B fragments: h limbs ----
        bf16x8 bh0 = *reinterpret_cast<const bf16x8*>(&hhi[cur][lr][lg * 8]);
        bf16x8 bh1 = *reinterpret_cast<const bf16x8*>(&hhi[cur][lr][32 + lg * 8]);
        bf16x8 bl0 = *reinterpret_cast<const bf16x8*>(&hlo[cur][lr][lg * 8]);
        bf16x8 bl1 = *reinterpret_cast<const bf16x8*>(&hlo[cur][lr][32 + lg * 8]);

        // ---- gx for (seq lr, 2 owned units): 24 FMAs ----
        float gxv[3][2];
        #pragma unroll
        for (int i = 0; i < 3; ++i) {
            #pragma unroll
            for (int k = 0; k < 2; ++k) {
                const float c0 = (i < 2) ? cbrz[i][k] : cbx[k];
                gxv[i][k] = fmaf(wihc[i][k][0], xc.x, fmaf(wihc[i][k][1], xc.y,
                            fmaf(wihc[i][k][2], xc.z, fmaf(wihc[i][k][3], xc.w, c0))));
            }
        }

        // ---- 12 MFMAs (identical in paired waves): 6 independent depth-2 chains ----
        const f32x4 z4 = {0.f, 0.f, 0.f, 0.f};
        f32x4 aR  = __builtin_amdgcn_mfma_f32_16x16x32_bf16(awh[0][0], bh0, z4, 0,0,0);
        f32x4 aZ  = __builtin_amdgcn_mfma_f32_16x16x32_bf16(awh[1][0], bh0, z4, 0,0,0);
        f32x4 aN  = __builtin_amdgcn_mfma_f32_16x16x32_bf16(awh[2][0], bh0, z4, 0,0,0);
        f32x4 aRc = __builtin_amdgcn_mfma_f32_16x16x32_bf16(awh[0][0], bl0, z4, 0,0,0);
        f32x4 aZc = __builtin_amdgcn_mfma_f32_16x16x32_bf16(awh[1][0], bl0, z4, 0,0,0);
        f32x4 aNc = __builtin_amdgcn_mfma_f32_16x16x32_bf16(awh[2][0], bl0, z4, 0,0,0);
        aR  = __builtin_amdgcn_mfma_f32_16x16x32_bf16(awh[0][1], bh1, aR , 0,0,0);
        aZ  = __builtin_amdgcn_mfma_f32_16x16x32_bf16(awh[1][1], bh1, aZ , 0,0,0);
        aN  = __builtin_amdgcn_mfma_f32_16x16x32_bf16(awh[2][1], bh1, aN , 0,0,0);
        aRc = __builtin_amdgcn_mfma_f32_16x16x32_bf16(awh[0][1], bl1, aRc, 0,0,0);
        aZc = __builtin_amdgcn_mfma_f32_16x16x32_bf16(awh[1][1], bl1, aZc, 0,0,0);
        aNc = __builtin_amdgcn_mfma_f32_16x16x32_bf16(awh[2][1], bl1, aNc, 0,0,0);

        // ---- gates for my 2 C rows (compile-time acc indices via uniform branch) ----
        unsigned short hib[2], lob[2];
#define GATE_ONE(K, C)                                                          \
        {                                                                       \
            float sR  = (aR[C] + aRc[C]) + gxv[0][K];                           \
            float sZ  = (aZ[C] + aZc[C]) + gxv[1][K];                           \
            float ghn = (aN[C] + aNc[C]) + cbh[K];                              \
            float rg = __builtin_amdgcn_rcpf(1.0f + __builtin_amdgcn_exp2f(-sR)); \
            float ez = __builtin_amdgcn_exp2f(-sZ);                             \
            float na = fmaf(rg, ghn, gxv[2][K]);                                \
            float e  = __builtin_amdgcn_exp2f(-na);                             \
            float nn = fmaf(2.0f, __builtin_amdgcn_rcpf(1.0f + e), -1.0f);      \
            float z  = __builtin_amdgcn_rcpf(1.0f + ez);                        \
            float hn = fmaf(z, hreg[K] - nn, nn);                               \
            hreg[K] = hn;                                                       \
            split2(hn, hib[K], lob[K]);                                         \
        }
        if (wg == 0) { GATE_ONE(0, 0) GATE_ONE(1, 1) }
        else         { GATE_ONE(0, 2) GATE_ONE(1, 3) }
#undef GATE_ONE
        unsigned ph = (unsigned)hib[0] | ((unsigned)hib[1] << 16);
        unsigned pl = (unsigned)lob[0] | ((unsigned)lob[1] << 16);
        *reinterpret_cast<unsigned*>(&hhi[nxt][lr][ub]) = ph;   // h[s=lr][ub..ub+1] hi
        *reinterpret_cast<unsigned*>(&hlo[nxt][lr][ub]) = pl;   // lo
        xc = xn;
        __syncthreads();   // h_{t+1} limbs visible; buf[cur] free next iteration
    }

    // ---- epilogue: out = h @ W_enc^T + b_enc (512 outputs, 1 per thread) ----
    hsf[lr][ub]     = hreg[0];
    hsf[lr][ub + 1] = hreg[1];
    __syncthreads();
    {
        const int s = tid >> 5, li = tid & 31;
        float a = b_enc[li];
        #pragma unroll
        for (int k = 0; k < HH; ++k)
            a = fmaf(hsf[s][k], W_enc[li * HH + k], a);
        out[(bid * SB + s) * LL + li] = a;
    }
}

extern "C" void kernel_launch(void* const* d_in, const int* in_sizes, int n_in,
                              void* d_out, int out_size, void* d_ws, size_t ws_size,
                              hipStream_t stream) {
    const float* xg    = (const float*)d_in[0];
    const float* W_ih  = (const float*)d_in[1];
    const float* W_hh  = (const float*)d_in[2];
    const float* b_ih  = (const float*)d_in[3];
    const float* b_hh  = (const float*)d_in[4];
    const float* W_enc = (const float*)d_in[5];
    const float* b_enc = (const float*)d_in[6];
    float* out = (float*)d_out;

    dim3 grid(8 * BPB), block(512);   // 256 blocks x 8 waves -> 2 waves/SIMD, all CUs
    hipLaunchKernelGGL(gru_traj_kernel, grid, block, 0, stream,
                       xg, W_ih, W_hh, b_ih, b_hh, W_enc, b_enc, out);
}

// Round 13
// 109.628 us; speedup vs baseline: 1.1699x; 1.1699x over previous
//
#include <hip/hip_runtime.h>

#define TT 200
#define NN 512
#define DD 4
#define HH 64
#define LL 32
#define SB 16                // sequences per block (fills MFMA dim)
#define BPB (NN / SB)        // 32 blocks per batch
#define KP 72                // ushort pitch per h row (144B = 9*16B)
#define LOG2E 1.44269504088896340736f

typedef short bf16x8 __attribute__((ext_vector_type(8)));
typedef float f32x4 __attribute__((ext_vector_type(4)));

union U8 { unsigned short s[8]; unsigned u[4]; bf16x8 v; };

// f32 -> (hi, lo) bf16 limbs by truncation
__device__ __forceinline__ void split2(float x, unsigned short& hi, unsigned short& lo) {
    unsigned u = __float_as_uint(x);
    hi = (unsigned short)(u >> 16);
    float lf = x - __uint_as_float(u & 0xffff0000u);
    lo = (unsigned short)(__float_as_uint(lf) >> 16);
}

__global__ __launch_bounds__(512, 1)
void gru_traj_kernel(const float* __restrict__ xg,    // (B,T,N,D)
                     const float* __restrict__ W_ih,  // (192,4)
                     const float* __restrict__ W_hh,  // (192,64)
                     const float* __restrict__ b_ih,  // (192,)
                     const float* __restrict__ b_hh,  // (192,)
                     const float* __restrict__ W_enc, // (32,64)
                     const float* __restrict__ b_enc, // (32,)
                     float* __restrict__ out)         // (B,N,32)
{
    __shared__ __align__(16) unsigned short hhi[2][SB][KP];   // h hi-limbs (dbuf)
    __shared__ __align__(16) unsigned short hlo[2][SB][KP];   // h lo-limbs
    __shared__ __align__(16) float hsf[SB][HH + 4];           // f32 h for epilogue

    const int tid = threadIdx.x;
    const int bid = blockIdx.x;
    const int b   = bid >> 5;                // bid / BPB
    const int n0  = (bid & (BPB - 1)) * SB;

    const int w  = tid >> 6;     // wave 0..7
    const int wq = w & 3;        // unit-group 16wq..16wq+15 (C tile rows)
    const int wg = w >> 2;       // row-half: this wave finishes C rows {2wg, 2wg+1}
    const int l  = tid & 63;
    const int lr = l & 15;       // A-row / B-col (seq) / C-col (seq)
    const int lg = l >> 4;       // k-group (A/B) and C row-group
    const int u0 = 16 * wq + lg * 4;   // first of 4 C rows in this lane's acc
    const int ub = u0 + 2 * wg;        // first of 2 owned units (gate phase)

    const float sc[3] = { LOG2E, LOG2E, 2.0f * LOG2E };

    // ---- A statics: W_hh hi-limbs (identical in paired waves, same wq) ----
    bf16x8 awh[3][2];
    #pragma unroll
    for (int i = 0; i < 3; ++i) {
        const int g = i * 64 + 16 * wq + lr;
        #pragma unroll
        for (int kc = 0; kc < 2; ++kc) {
            const float* p = W_hh + g * HH + kc * 32 + lg * 8;
            U8 uh;
            #pragma unroll
            for (int j = 0; j < 8; ++j) {
                unsigned short hi, lo;
                split2(p[j] * sc[i], hi, lo);
                uh.s[j] = hi; (void)lo;
            }
            awh[i][kc] = uh.v;
        }
    }
    // ---- per-lane gate constants for the 2 owned units (g = i*64 + ub + k) ----
    float wihc[3][2][4], cbrz[2][2], cbx[2], cbh[2];
    #pragma unroll
    for (int i = 0; i < 3; ++i) {
        #pragma unroll
        for (int k = 0; k < 2; ++k) {
            const int g = i * 64 + ub + k;
            #pragma unroll
            for (int d = 0; d < 4; ++d) wihc[i][k][d] = W_ih[g * DD + d] * sc[i];
            if (i < 2) cbrz[i][k] = (b_ih[g] + b_hh[g]) * sc[i];
            else       { cbx[k] = b_ih[g] * sc[2]; cbh[k] = b_hh[g] * sc[2]; }
        }
    }

    // ---- init: zero h limb buffers (h0 = 0) ----
    for (int idx = tid; idx < 2 * SB * KP / 2; idx += 512) {
        reinterpret_cast<unsigned*>(hhi)[idx] = 0u;
        reinterpret_cast<unsigned*>(hlo)[idx] = 0u;
    }
    float hreg[2] = {0.f, 0.f};   // h[s = lr][ub + k]

    // ---- x_0 into registers (lane's seq = n0 + lr) ----
    float4 xc = *reinterpret_cast<const float4*>(
        xg + ((size_t)(b * TT) * NN + n0 + lr) * DD);
    __syncthreads();

    const bool hihalf = (wg != 0);   // loop-invariant per-lane bool -> cndmask selects

    #pragma unroll 2
    for (int t = 0; t < TT; ++t) {
        const int cur = t & 1, nxt = cur ^ 1;
        const int tn  = (t + 1 < TT) ? t + 1 : t;

        // prefetch x_{t+1}
        float4 xn = *reinterpret_cast<const float4*>(
            xg + ((size_t)(b * TT + tn) * NN + n0 + lr) * DD);

        // ---- B fragments: h limbs ----
        bf16x8 bh0 = *reinterpret_cast<const bf16x8*>(&hhi[cur][lr][lg * 8]);
        bf16x8 bh1 = *reinterpret_cast<const bf16x8*>(&hhi[cur][lr][32 + lg * 8]);
        bf16x8 bl0 = *reinterpret_cast<const bf16x8*>(&hlo[cur][lr][lg * 8]);
        bf16x8 bl1 = *reinterpret_cast<const bf16x8*>(&hlo[cur][lr][32 + lg * 8]);

        // ---- gx for (seq lr, 2 owned units): 24 FMAs ----
        float gxv[3][2];
        #pragma unroll
        for (int i = 0; i < 3; ++i) {
            #pragma unroll
            for (int k = 0; k < 2; ++k) {
                const float c0 = (i < 2) ? cbrz[i][k] : cbx[k];
                gxv[i][k] = fmaf(wihc[i][k][0], xc.x, fmaf(wihc[i][k][1], xc.y,
                            fmaf(wihc[i][k][2], xc.z, fmaf(wihc[i][k][3], xc.w, c0))));
            }
        }

        // ---- 12 MFMAs (duplicated in paired waves): 6 independent depth-2 chains ----
        const f32x4 z4 = {0.f, 0.f, 0.f, 0.f};
        f32x4 aR  = __builtin_amdgcn_mfma_f32_16x16x32_bf16(awh[0][0], bh0, z4, 0,0,0);
        f32x4 aZ  = __builtin_amdgcn_mfma_f32_16x16x32_bf16(awh[1][0], bh0, z4, 0,0,0);
        f32x4 aN  = __builtin_amdgcn_mfma_f32_16x16x32_bf16(awh[2][0], bh0, z4, 0,0,0);
        f32x4 aRc = __builtin_amdgcn_mfma_f32_16x16x32_bf16(awh[0][0], bl0, z4, 0,0,0);
        f32x4 aZc = __builtin_amdgcn_mfma_f32_16x16x32_bf16(awh[1][0], bl0, z4, 0,0,0);
        f32x4 aNc = __builtin_amdgcn_mfma_f32_16x16x32_bf16(awh[2][0], bl0, z4, 0,0,0);
        aR  = __builtin_amdgcn_mfma_f32_16x16x32_bf16(awh[0][1], bh1, aR , 0,0,0);
        aZ  = __builtin_amdgcn_mfma_f32_16x16x32_bf16(awh[1][1], bh1, aZ , 0,0,0);
        aN  = __builtin_amdgcn_mfma_f32_16x16x32_bf16(awh[2][1], bh1, aN , 0,0,0);
        aRc = __builtin_amdgcn_mfma_f32_16x16x32_bf16(awh[0][1], bl1, aRc, 0,0,0);
        aZc = __builtin_amdgcn_mfma_f32_16x16x32_bf16(awh[1][1], bl1, aZc, 0,0,0);
        aNc = __builtin_amdgcn_mfma_f32_16x16x32_bf16(awh[2][1], bl1, aNc, 0,0,0);

        // ---- row-pair select: 12 cndmasks, compile-time vector indices ----
        #define SEL(V, K) (hihalf ? (V)[2 + (K)] : (V)[K])
        unsigned short hib[2], lob[2];
        #pragma unroll
        for (int k = 0; k < 2; ++k) {
            float vR  = (k ? SEL(aR , 1) : SEL(aR , 0));
            float vRc = (k ? SEL(aRc, 1) : SEL(aRc, 0));
            float vZ  = (k ? SEL(aZ , 1) : SEL(aZ , 0));
            float vZc = (k ? SEL(aZc, 1) : SEL(aZc, 0));
            float vN  = (k ? SEL(aN , 1) : SEL(aN , 0));
            float vNc = (k ? SEL(aNc, 1) : SEL(aNc, 0));
            float sR  = (vR + vRc) + gxv[0][k];
            float sZ  = (vZ + vZc) + gxv[1][k];
            float ghn = (vN + vNc) + cbh[k];
            float rg = __builtin_amdgcn_rcpf(1.0f + __builtin_amdgcn_exp2f(-sR));
            float ez = __builtin_amdgcn_exp2f(-sZ);
            float na = fmaf(rg, ghn, gxv[2][k]);
            float e  = __builtin_amdgcn_exp2f(-na);
            float nn = fmaf(2.0f, __builtin_amdgcn_rcpf(1.0f + e), -1.0f);  // tanh
            float z  = __builtin_amdgcn_rcpf(1.0f + ez);
            float hn = fmaf(z, hreg[k] - nn, nn);       // (1-z)n + z h
            hreg[k] = hn;
            split2(hn, hib[k], lob[k]);
        }
        #undef SEL
        unsigned ph = (unsigned)hib[0] | ((unsigned)hib[1] << 16);
        unsigned pl = (unsigned)lob[0] | ((unsigned)lob[1] << 16);
        *reinterpret_cast<unsigned*>(&hhi[nxt][lr][ub]) = ph;   // h[s=lr][ub..ub+1] hi
        *reinterpret_cast<unsigned*>(&hlo[nxt][lr][ub]) = pl;   // lo
        xc = xn;
        __syncthreads();   // h_{t+1} limbs visible; buf[cur] free next iteration
    }

    // ---- epilogue: out = h @ W_enc^T + b_enc (512 outputs, 1 per thread) ----
    hsf[lr][ub]     = hreg[0];
    hsf[lr][ub + 1] = hreg[1];
    __syncthreads();
    {
        const int s = tid >> 5, li = tid & 31;
        float a = b_enc[li];
        #pragma unroll
        for (int k = 0; k < HH; ++k)
            a = fmaf(hsf[s][k], W_enc[li * HH + k], a);
        out[(bid * SB + s) * LL + li] = a;
    }
}

extern "C" void kernel_launch(void* const* d_in, const int* in_sizes, int n_in,
                              void* d_out, int out_size, void* d_ws, size_t ws_size,
                              hipStream_t stream) {
    const float* xg    = (const float*)d_in[0];
    const float* W_ih  = (const float*)d_in[1];
    const float* W_hh  = (const float*)d_in[2];
    const float* b_ih  = (const float*)d_in[3];
    const float* b_hh  = (const float*)d_in[4];
    const float* W_enc = (const float*)d_in[5];
    const float* b_enc = (const float*)d_in[6];
    float* out = (float*)d_out;

    dim3 grid(8 * BPB), block(512);   // 256 blocks x 8 waves -> 2 waves/SIMD, all CUs
    hipLaunchKernelGGL(gru_traj_kernel, grid, block, 0, stream,
                       xg, W_ih, W_hh, b_ih, b_hh, W_enc, b_enc, out);
}

// Round 14
// 105.097 us; speedup vs baseline: 1.2203x; 1.0431x over previous
//
#include <hip/hip_runtime.h>

#define TT 200
#define NN 512
#define DD 4
#define HH 64
#define LL 32
#define SB 16                // sequences per block (fills MFMA dim)
#define BPB (NN / SB)        // 32 blocks per batch
#define KP 72                // ushort pitch per h row (144B = 9*16B)
#define LOG2E 1.44269504088896340736f

typedef short bf16x8 __attribute__((ext_vector_type(8)));
typedef float f32x4 __attribute__((ext_vector_type(4)));

union U8 { unsigned short s[8]; unsigned u[4]; bf16x8 v; };

// f32 -> (hi, lo) bf16 limbs by truncation
__device__ __forceinline__ void split2(float x, unsigned short& hi, unsigned short& lo) {
    unsigned u = __float_as_uint(x);
    hi = (unsigned short)(u >> 16);
    float lf = x - __uint_as_float(u & 0xffff0000u);
    lo = (unsigned short)(__float_as_uint(lf) >> 16);
}

__global__ __launch_bounds__(512, 1)
void gru_traj_kernel(const float* __restrict__ xg,    // (B,T,N,D)
                     const float* __restrict__ W_ih,  // (192,4)
                     const float* __restrict__ W_hh,  // (192,64)
                     const float* __restrict__ b_ih,  // (192,)
                     const float* __restrict__ b_hh,  // (192,)
                     const float* __restrict__ W_enc, // (32,64)
                     const float* __restrict__ b_enc, // (32,)
                     float* __restrict__ out)         // (B,N,32)
{
    __shared__ __align__(16) unsigned short hhi[2][SB][KP];   // h hi-limbs (dbuf)
    __shared__ __align__(16) unsigned short hlo[2][SB][KP];   // h lo-limbs
    __shared__ __align__(16) float hsf[SB][HH + 4];           // f32 h for epilogue

    const int tid = threadIdx.x;
    const int bid = blockIdx.x;
    const int b   = bid >> 5;                // bid / BPB
    const int n0  = (bid & (BPB - 1)) * SB;

    const int w  = tid >> 6;     // wave 0..7
    const int wq = w & 3;        // unit-group 16wq..16wq+15 (C tile rows)
    const int wg = w >> 2;       // row-half: this wave finishes C rows {2wg, 2wg+1}
    const int l  = tid & 63;
    const int lr = l & 15;       // A-row / B-col (seq) / C-col (seq)
    const int lg = l >> 4;       // k-group (A/B) and C row-group
    const int u0 = 16 * wq + lg * 4;   // first of 4 C rows in this lane's acc
    const int ub = u0 + 2 * wg;        // first of 2 owned units (gate phase)

    const float sc[3] = { LOG2E, LOG2E, 2.0f * LOG2E };

    // ---- A statics: W_hh hi-limbs (identical in paired waves, same wq) ----
    bf16x8 awh[3][2];
    #pragma unroll
    for (int i = 0; i < 3; ++i) {
        const int g = i * 64 + 16 * wq + lr;
        #pragma unroll
        for (int kc = 0; kc < 2; ++kc) {
            const float* p = W_hh + g * HH + kc * 32 + lg * 8;
            U8 uh;
            #pragma unroll
            for (int j = 0; j < 8; ++j) {
                unsigned short hi, lo;
                split2(p[j] * sc[i], hi, lo);
                uh.s[j] = hi; (void)lo;
            }
            awh[i][kc] = uh.v;
        }
    }
    // ---- per-lane gate constants for the 2 owned units (g = i*64 + ub + k) ----
    float wihc[3][2][4], cbrz[2][2], cbx[2], cbh[2];
    #pragma unroll
    for (int i = 0; i < 3; ++i) {
        #pragma unroll
        for (int k = 0; k < 2; ++k) {
            const int g = i * 64 + ub + k;
            #pragma unroll
            for (int d = 0; d < 4; ++d) wihc[i][k][d] = W_ih[g * DD + d] * sc[i];
            if (i < 2) cbrz[i][k] = (b_ih[g] + b_hh[g]) * sc[i];
            else       { cbx[k] = b_ih[g] * sc[2]; cbh[k] = b_hh[g] * sc[2]; }
        }
    }

    // ---- init: zero h limb buffers (h0 = 0) ----
    for (int idx = tid; idx < 2 * SB * KP / 2; idx += 512) {
        reinterpret_cast<unsigned*>(hhi)[idx] = 0u;
        reinterpret_cast<unsigned*>(hlo)[idx] = 0u;
    }
    float hreg[2] = {0.f, 0.f};   // h[s = lr][ub + k]

    // ---- x_0 into registers (lane's seq = n0 + lr) ----
    float4 xc = *reinterpret_cast<const float4*>(
        xg + ((size_t)(b * TT) * NN + n0 + lr) * DD);
    __syncthreads();

    const bool hihalf = (wg != 0);   // loop-invariant per-lane bool -> cndmask selects
    const f32x4 z4 = {0.f, 0.f, 0.f, 0.f};

    #pragma unroll 2
    for (int t = 0; t < TT; ++t) {
        const int cur = t & 1, nxt = cur ^ 1;
        const int tn  = (t + 1 < TT) ? t + 1 : t;

        // prefetch x_{t+1}
        float4 xn = *reinterpret_cast<const float4*>(
            xg + ((size_t)(b * TT + tn) * NN + n0 + lr) * DD);

        // ---- B fragments: h limbs ----
        bf16x8 bh0 = *reinterpret_cast<const bf16x8*>(&hhi[cur][lr][lg * 8]);
        bf16x8 bh1 = *reinterpret_cast<const bf16x8*>(&hhi[cur][lr][32 + lg * 8]);
        bf16x8 bl0 = *reinterpret_cast<const bf16x8*>(&hlo[cur][lr][lg * 8]);
        bf16x8 bl1 = *reinterpret_cast<const bf16x8*>(&hlo[cur][lr][32 + lg * 8]);

        // ---- gx for (seq lr, 2 owned units): 24 FMAs ----
        float gxv[3][2];
        #pragma unroll
        for (int i = 0; i < 3; ++i) {
            #pragma unroll
            for (int k = 0; k < 2; ++k) {
                const float c0 = (i < 2) ? cbrz[i][k] : cbx[k];
                gxv[i][k] = fmaf(wihc[i][k][0], xc.x, fmaf(wihc[i][k][1], xc.y,
                            fmaf(wihc[i][k][2], xc.z, fmaf(wihc[i][k][3], xc.w, c0))));
            }
        }

        // ---- 12 MFMAs: 3 depth-4 chains (lo products first), single accumulator each ----
        f32x4 aR = __builtin_amdgcn_mfma_f32_16x16x32_bf16(awh[0][0], bl0, z4, 0,0,0);
        f32x4 aZ = __builtin_amdgcn_mfma_f32_16x16x32_bf16(awh[1][0], bl0, z4, 0,0,0);
        f32x4 aN = __builtin_amdgcn_mfma_f32_16x16x32_bf16(awh[2][0], bl0, z4, 0,0,0);
        aR = __builtin_amdgcn_mfma_f32_16x16x32_bf16(awh[0][1], bl1, aR, 0,0,0);
        aZ = __builtin_amdgcn_mfma_f32_16x16x32_bf16(awh[1][1], bl1, aZ, 0,0,0);
        aN = __builtin_amdgcn_mfma_f32_16x16x32_bf16(awh[2][1], bl1, aN, 0,0,0);
        aR = __builtin_amdgcn_mfma_f32_16x16x32_bf16(awh[0][0], bh0, aR, 0,0,0);
        aZ = __builtin_amdgcn_mfma_f32_16x16x32_bf16(awh[1][0], bh0, aZ, 0,0,0);
        aN = __builtin_amdgcn_mfma_f32_16x16x32_bf16(awh[2][0], bh0, aN, 0,0,0);
        aR = __builtin_amdgcn_mfma_f32_16x16x32_bf16(awh[0][1], bh1, aR, 0,0,0);
        aZ = __builtin_amdgcn_mfma_f32_16x16x32_bf16(awh[1][1], bh1, aZ, 0,0,0);
        aN = __builtin_amdgcn_mfma_f32_16x16x32_bf16(awh[2][1], bh1, aN, 0,0,0);

        // ---- row-pair select: 6 cndmasks (compile-time vector indices) ----
        float vR0 = hihalf ? aR[2] : aR[0];
        float vR1 = hihalf ? aR[3] : aR[1];
        float vZ0 = hihalf ? aZ[2] : aZ[0];
        float vZ1 = hihalf ? aZ[3] : aZ[1];
        float vN0 = hihalf ? aN[2] : aN[0];
        float vN1 = hihalf ? aN[3] : aN[1];

        // ---- gates (exp2 domain) for the 2 owned rows ----
        float hn0, hn1;
        {
            float sR  = vR0 + gxv[0][0];
            float sZ  = vZ0 + gxv[1][0];
            float ghn = vN0 + cbh[0];
            float rg = __builtin_amdgcn_rcpf(1.0f + __builtin_amdgcn_exp2f(-sR));
            float ez = __builtin_amdgcn_exp2f(-sZ);
            float na = fmaf(rg, ghn, gxv[2][0]);
            float e  = __builtin_amdgcn_exp2f(-na);
            float nn = fmaf(2.0f, __builtin_amdgcn_rcpf(1.0f + e), -1.0f);  // tanh
            float z  = __builtin_amdgcn_rcpf(1.0f + ez);
            hn0 = fmaf(z, hreg[0] - nn, nn);
            hreg[0] = hn0;
        }
        {
            float sR  = vR1 + gxv[0][1];
            float sZ  = vZ1 + gxv[1][1];
            float ghn = vN1 + cbh[1];
            float rg = __builtin_amdgcn_rcpf(1.0f + __builtin_amdgcn_exp2f(-sR));
            float ez = __builtin_amdgcn_exp2f(-sZ);
            float na = fmaf(rg, ghn, gxv[2][1]);
            float e  = __builtin_amdgcn_exp2f(-na);
            float nn = fmaf(2.0f, __builtin_amdgcn_rcpf(1.0f + e), -1.0f);
            float z  = __builtin_amdgcn_rcpf(1.0f + ez);
            hn1 = fmaf(z, hreg[1] - nn, nn);
            hreg[1] = hn1;
        }

        // ---- limb split + pack via v_perm (selector 0x07060302: bytes 3:2 of each) ----
        unsigned ph = __builtin_amdgcn_perm(__float_as_uint(hn1), __float_as_uint(hn0),
                                            0x07060302u);
        float lf0 = hn0 - __uint_as_float(__float_as_uint(hn0) & 0xffff0000u);
        float lf1 = hn1 - __uint_as_float(__float_as_uint(hn1) & 0xffff0000u);
        unsigned pl = __builtin_amdgcn_perm(__float_as_uint(lf1), __float_as_uint(lf0),
                                            0x07060302u);
        *reinterpret_cast<unsigned*>(&hhi[nxt][lr][ub]) = ph;   // h[s=lr][ub..ub+1] hi
        *reinterpret_cast<unsigned*>(&hlo[nxt][lr][ub]) = pl;   // lo
        xc = xn;
        __syncthreads();   // h_{t+1} limbs visible; buf[cur] free next iteration
    }

    // ---- epilogue: out = h @ W_enc^T + b_enc (512 outputs, 1 per thread) ----
    hsf[lr][ub]     = hreg[0];
    hsf[lr][ub + 1] = hreg[1];
    __syncthreads();
    {
        const int s = tid >> 5, li = tid & 31;
        float a = b_enc[li];
        #pragma unroll
        for (int k = 0; k < HH; ++k)
            a = fmaf(hsf[s][k], W_enc[li * HH + k], a);
        out[(bid * SB + s) * LL + li] = a;
    }
}

extern "C" void kernel_launch(void* const* d_in, const int* in_sizes, int n_in,
                              void* d_out, int out_size, void* d_ws, size_t ws_size,
                              hipStream_t stream) {
    const float* xg    = (const float*)d_in[0];
    const float* W_ih  = (const float*)d_in[1];
    const float* W_hh  = (const float*)d_in[2];
    const float* b_ih  = (const float*)d_in[3];
    const float* b_hh  = (const float*)d_in[4];
    const float* W_enc = (const float*)d_in[5];
    const float* b_enc = (const float*)d_in[6];
    float* out = (float*)d_out;

    dim3 grid(8 * BPB), block(512);   // 256 blocks x 8 waves -> 2 waves/SIMD, all CUs
    hipLaunchKernelGGL(gru_traj_kernel, grid, block, 0, stream,
                       xg, W_ih, W_hh, b_ih, b_hh, W_enc, b_enc, out);
}

// Round 15
// 101.812 us; speedup vs baseline: 1.2597x; 1.0323x over previous
//
#include <hip/hip_runtime.h>

#define TT 200
#define NN 512
#define DD 4
#define HH 64
#define LL 32
#define SB 8                 // sequences per block (B-cols duplicated to fill M=16)
#define BPB (NN / SB)        // 64 blocks per batch
#define KP 72                // ushort pitch per h row (144B = 9*16B)
#define LOG2E 1.44269504088896340736f

typedef short bf16x8 __attribute__((ext_vector_type(8)));
typedef float f32x4 __attribute__((ext_vector_type(4)));

union U8 { unsigned short s[8]; unsigned u[4]; bf16x8 v; };

// f32 -> (hi, lo) bf16 limbs by truncation
__device__ __forceinline__ void split2(float x, unsigned short& hi, unsigned short& lo) {
    unsigned u = __float_as_uint(x);
    hi = (unsigned short)(u >> 16);
    float lf = x - __uint_as_float(u & 0xffff0000u);
    lo = (unsigned short)(__float_as_uint(lf) >> 16);
}

__global__ __launch_bounds__(256, 2)
void gru_traj_kernel(const float* __restrict__ xg,    // (B,T,N,D)
                     const float* __restrict__ W_ih,  // (192,4)
                     const float* __restrict__ W_hh,  // (192,64)
                     const float* __restrict__ b_ih,  // (192,)
                     const float* __restrict__ b_hh,  // (192,)
                     const float* __restrict__ W_enc, // (32,64)
                     const float* __restrict__ b_enc, // (32,)
                     float* __restrict__ out)         // (B,N,32)
{
    __shared__ __align__(16) unsigned short hhi[2][SB][KP];   // h hi-limbs (dbuf)
    __shared__ __align__(16) unsigned short hlo[2][SB][KP];   // h lo-limbs
    __shared__ __align__(16) float hsf[SB][HH + 4];           // f32 h for epilogue

    const int tid = threadIdx.x;
    const int bid = blockIdx.x;
    const int b   = bid >> 6;                // bid / BPB
    const int n0  = (bid & (BPB - 1)) * SB;  // first seq of this block

    const int w  = tid >> 6;     // wave 0..3 -> unit-group 16w..16w+15 (C rows)
    const int l  = tid & 63;
    const int lr = l & 15;       // A-row / B-col / C-col within tile
    const int lg = l >> 4;       // k-group (A/B) and C row-group
    const int s  = l & 7;        // owned seq (lanes lr and lr+8 share a seq)
    const int hi8 = (lr >> 3) & 1;           // 0: rows {0,1}; 1: rows {2,3} of acc
    const int u0 = 16 * w + lg * 4;          // first of 4 C rows in this lane's acc
    const int ub = u0 + 2 * hi8;             // first of 2 owned units (gate phase)

    const float sc[3] = { LOG2E, LOG2E, 2.0f * LOG2E };

    // ---- A statics: W_hh hi-limbs ----
    bf16x8 awh[3][2];
    #pragma unroll
    for (int i = 0; i < 3; ++i) {
        const int g = i * 64 + 16 * w + lr;
        #pragma unroll
        for (int kc = 0; kc < 2; ++kc) {
            const float* p = W_hh + g * HH + kc * 32 + lg * 8;
            U8 uh;
            #pragma unroll
            for (int j = 0; j < 8; ++j) {
                unsigned short hh, ll_;
                split2(p[j] * sc[i], hh, ll_);
                uh.s[j] = hh; (void)ll_;
            }
            awh[i][kc] = uh.v;
        }
    }
    // ---- per-lane gate constants for the 2 owned units (g = i*64 + ub + k) ----
    float wihc[3][2][4], cbrz[2][2], cbx[2], cbh[2];
    #pragma unroll
    for (int i = 0; i < 3; ++i) {
        #pragma unroll
        for (int k = 0; k < 2; ++k) {
            const int g = i * 64 + ub + k;
            #pragma unroll
            for (int d = 0; d < 4; ++d) wihc[i][k][d] = W_ih[g * DD + d] * sc[i];
            if (i < 2) cbrz[i][k] = (b_ih[g] + b_hh[g]) * sc[i];
            else       { cbx[k] = b_ih[g] * sc[2]; cbh[k] = b_hh[g] * sc[2]; }
        }
    }

    // ---- init: zero h limb buffers (h0 = 0) ----
    for (int idx = tid; idx < 2 * SB * KP / 2; idx += 256) {
        reinterpret_cast<unsigned*>(hhi)[idx] = 0u;
        reinterpret_cast<unsigned*>(hlo)[idx] = 0u;
    }
    float hreg[2] = {0.f, 0.f};   // h[s][ub + k]

    // ---- x_0 into registers (lane's seq = n0 + s; lane pairs duplicate) ----
    float4 xc = *reinterpret_cast<const float4*>(
        xg + ((size_t)(b * TT) * NN + n0 + s) * DD);
    __syncthreads();

    const bool hi8b = (hi8 != 0);   // loop-invariant per-lane bool -> cndmask selects
    const f32x4 z4 = {0.f, 0.f, 0.f, 0.f};

    #pragma unroll 2
    for (int t = 0; t < TT; ++t) {
        const int cur = t & 1, nxt = cur ^ 1;
        const int tn  = (t + 1 < TT) ? t + 1 : t;

        // prefetch x_{t+1}
        float4 xn = *reinterpret_cast<const float4*>(
            xg + ((size_t)(b * TT + tn) * NN + n0 + s) * DD);

        // ---- B fragments: h limbs; row s (lanes lr>=8 broadcast-read row lr-8) ----
        bf16x8 bh0 = *reinterpret_cast<const bf16x8*>(&hhi[cur][s][lg * 8]);
        bf16x8 bh1 = *reinterpret_cast<const bf16x8*>(&hhi[cur][s][32 + lg * 8]);
        bf16x8 bl0 = *reinterpret_cast<const bf16x8*>(&hlo[cur][s][lg * 8]);
        bf16x8 bl1 = *reinterpret_cast<const bf16x8*>(&hlo[cur][s][32 + lg * 8]);

        // ---- gx for (seq s, 2 owned units): 24 FMAs ----
        float gxv[3][2];
        #pragma unroll
        for (int i = 0; i < 3; ++i) {
            #pragma unroll
            for (int k = 0; k < 2; ++k) {
                const float c0 = (i < 2) ? cbrz[i][k] : cbx[k];
                gxv[i][k] = fmaf(wihc[i][k][0], xc.x, fmaf(wihc[i][k][1], xc.y,
                            fmaf(wihc[i][k][2], xc.z, fmaf(wihc[i][k][3], xc.w, c0))));
            }
        }

        // ---- 12 MFMAs: 3 depth-4 chains (lo products first) ----
        f32x4 aR = __builtin_amdgcn_mfma_f32_16x16x32_bf16(awh[0][0], bl0, z4, 0,0,0);
        f32x4 aZ = __builtin_amdgcn_mfma_f32_16x16x32_bf16(awh[1][0], bl0, z4, 0,0,0);
        f32x4 aN = __builtin_amdgcn_mfma_f32_16x16x32_bf16(awh[2][0], bl0, z4, 0,0,0);
        aR = __builtin_amdgcn_mfma_f32_16x16x32_bf16(awh[0][1], bl1, aR, 0,0,0);
        aZ = __builtin_amdgcn_mfma_f32_16x16x32_bf16(awh[1][1], bl1, aZ, 0,0,0);
        aN = __builtin_amdgcn_mfma_f32_16x16x32_bf16(awh[2][1], bl1, aN, 0,0,0);
        aR = __builtin_amdgcn_mfma_f32_16x16x32_bf16(awh[0][0], bh0, aR, 0,0,0);
        aZ = __builtin_amdgcn_mfma_f32_16x16x32_bf16(awh[1][0], bh0, aZ, 0,0,0);
        aN = __builtin_amdgcn_mfma_f32_16x16x32_bf16(awh[2][0], bh0, aN, 0,0,0);
        aR = __builtin_amdgcn_mfma_f32_16x16x32_bf16(awh[0][1], bh1, aR, 0,0,0);
        aZ = __builtin_amdgcn_mfma_f32_16x16x32_bf16(awh[1][1], bh1, aZ, 0,0,0);
        aN = __builtin_amdgcn_mfma_f32_16x16x32_bf16(awh[2][1], bh1, aN, 0,0,0);

        // ---- row-pair select: 6 cndmasks (acc cols duplicate across lane halves) ----
        float vR0 = hi8b ? aR[2] : aR[0];
        float vR1 = hi8b ? aR[3] : aR[1];
        float vZ0 = hi8b ? aZ[2] : aZ[0];
        float vZ1 = hi8b ? aZ[3] : aZ[1];
        float vN0 = hi8b ? aN[2] : aN[0];
        float vN1 = hi8b ? aN[3] : aN[1];

        // ---- gates (exp2 domain) for the 2 owned rows ----
        float hn0, hn1;
        {
            float sR  = vR0 + gxv[0][0];
            float sZ  = vZ0 + gxv[1][0];
            float ghn = vN0 + cbh[0];
            float rg = __builtin_amdgcn_rcpf(1.0f + __builtin_amdgcn_exp2f(-sR));
            float ez = __builtin_amdgcn_exp2f(-sZ);
            float na = fmaf(rg, ghn, gxv[2][0]);
            float e  = __builtin_amdgcn_exp2f(-na);
            float nn = fmaf(2.0f, __builtin_amdgcn_rcpf(1.0f + e), -1.0f);  // tanh
            float z  = __builtin_amdgcn_rcpf(1.0f + ez);
            hn0 = fmaf(z, hreg[0] - nn, nn);
            hreg[0] = hn0;
        }
        {
            float sR  = vR1 + gxv[0][1];
            float sZ  = vZ1 + gxv[1][1];
            float ghn = vN1 + cbh[1];
            float rg = __builtin_amdgcn_rcpf(1.0f + __builtin_amdgcn_exp2f(-sR));
            float ez = __builtin_amdgcn_exp2f(-sZ);
            float na = fmaf(rg, ghn, gxv[2][1]);
            float e  = __builtin_amdgcn_exp2f(-na);
            float nn = fmaf(2.0f, __builtin_amdgcn_rcpf(1.0f + e), -1.0f);
            float z  = __builtin_amdgcn_rcpf(1.0f + ez);
            hn1 = fmaf(z, hreg[1] - nn, nn);
            hreg[1] = hn1;
        }

        // ---- limb split + pack via v_perm (bytes 3:2 of each float) ----
        unsigned ph = __builtin_amdgcn_perm(__float_as_uint(hn1), __float_as_uint(hn0),
                                            0x07060302u);
        float lf0 = hn0 - __uint_as_float(__float_as_uint(hn0) & 0xffff0000u);
        float lf1 = hn1 - __uint_as_float(__float_as_uint(hn1) & 0xffff0000u);
        unsigned pl = __builtin_amdgcn_perm(__float_as_uint(lf1), __float_as_uint(lf0),
                                            0x07060302u);
        *reinterpret_cast<unsigned*>(&hhi[nxt][s][ub]) = ph;   // h[s][ub..ub+1] hi
        *reinterpret_cast<unsigned*>(&hlo[nxt][s][ub]) = pl;   // lo
        xc = xn;
        __syncthreads();   // h_{t+1} limbs visible; buf[cur] free next iteration
    }

    // ---- epilogue: out = h @ W_enc^T + b_enc (256 outputs, 1 per thread) ----
    hsf[s][ub]     = hreg[0];
    hsf[s][ub + 1] = hreg[1];
    __syncthreads();
    {
        const int so = tid >> 5, li = tid & 31;
        float a = b_enc[li];
        #pragma unroll
        for (int k = 0; k < HH; ++k)
            a = fmaf(hsf[so][k], W_enc[li * HH + k], a);
        out[(bid * SB + so) * LL + li] = a;
    }
}

extern "C" void kernel_launch(void* const* d_in, const int* in_sizes, int n_in,
                              void* d_out, int out_size, void* d_ws, size_t ws_size,
                              hipStream_t stream) {
    const float* xg    = (const float*)d_in[0];
    const float* W_ih  = (const float*)d_in[1];
    const float* W_hh  = (const float*)d_in[2];
    const float* b_ih  = (const float*)d_in[3];
    const float* b_hh  = (const float*)d_in[4];
    const float* W_enc = (const float*)d_in[5];
    const float* b_enc = (const float*)d_in[6];
    float* out = (float*)d_out;

    dim3 grid(8 * BPB), block(256);   // 512 blocks -> 2 independent blocks/CU
    hipLaunchKernelGGL(gru_traj_kernel, grid, block, 0, stream,
                       xg, W_ih, W_hh, b_ih, b_hh, W_enc, b_enc, out);
}

// Round 16
// 95.153 us; speedup vs baseline: 1.3478x; 1.0700x over previous
//
#include <hip/hip_runtime.h>

#define TT 200
#define NN 512
#define DD 4
#define HH 64
#define LL 32
#define SB 8                 // sequences per block (B-cols duplicated to fill M=16)
#define BPB (NN / SB)        // 64 blocks per batch
#define KP 72                // ushort pitch per h row (144B = 9*16B)
#define LOG2E 1.44269504088896340736f

typedef short bf16x8 __attribute__((ext_vector_type(8)));
typedef float f32x4 __attribute__((ext_vector_type(4)));

union U8 { unsigned short s[8]; unsigned u[4]; bf16x8 v; };

// f32 -> (hi, lo) bf16 limbs by truncation
__device__ __forceinline__ void split2(float x, unsigned short& hi, unsigned short& lo) {
    unsigned u = __float_as_uint(x);
    hi = (unsigned short)(u >> 16);
    float lf = x - __uint_as_float(u & 0xffff0000u);
    lo = (unsigned short)(__float_as_uint(lf) >> 16);
}

__global__ __launch_bounds__(256, 2)
void gru_traj_kernel(const float* __restrict__ xg,    // (B,T,N,D)
                     const float* __restrict__ W_ih,  // (192,4)
                     const float* __restrict__ W_hh,  // (192,64)
                     const float* __restrict__ b_ih,  // (192,)
                     const float* __restrict__ b_hh,  // (192,)
                     const float* __restrict__ W_enc, // (32,64)
                     const float* __restrict__ b_enc, // (32,)
                     float* __restrict__ out)         // (B,N,32)
{
    __shared__ __align__(16) unsigned short hhi[2][SB][KP];   // h hi-limbs (dbuf)
    __shared__ __align__(16) unsigned short hlo[2][SB][KP];   // h lo-limbs
    __shared__ __align__(16) float hsf[SB][HH + 4];           // f32 h for epilogue

    const int tid = threadIdx.x;
    const int bid = blockIdx.x;
    const int b   = bid >> 6;                // bid / BPB
    const int n0  = (bid & (BPB - 1)) * SB;  // first seq of this block

    const int w  = tid >> 6;     // wave 0..3 -> unit-group 16w..16w+15 (C rows)
    const int l  = tid & 63;
    const int lr = l & 15;       // A-row / B-col / C-col within tile
    const int lg = l >> 4;       // k-group (A/B) and C row-group
    const int s  = l & 7;        // owned seq (lanes lr and lr+8 share a seq)
    const int hi8 = (lr >> 3) & 1;           // 0: rows {0,1}; 1: rows {2,3} of acc
    const int u0 = 16 * w + lg * 4;          // first of 4 C rows in this lane's acc
    const int ub = u0 + 2 * hi8;             // first of 2 owned units (gate phase)

    const float sc[3] = { LOG2E, LOG2E, 2.0f * LOG2E };

    // ---- A statics: W_hh hi-limbs ----
    bf16x8 awh[3][2];
    #pragma unroll
    for (int i = 0; i < 3; ++i) {
        const int g = i * 64 + 16 * w + lr;
        #pragma unroll
        for (int kc = 0; kc < 2; ++kc) {
            const float* p = W_hh + g * HH + kc * 32 + lg * 8;
            U8 uh;
            #pragma unroll
            for (int j = 0; j < 8; ++j) {
                unsigned short hh, ll_;
                split2(p[j] * sc[i], hh, ll_);
                uh.s[j] = hh; (void)ll_;
            }
            awh[i][kc] = uh.v;
        }
    }
    // ---- per-lane gate constants for the 2 owned units (g = i*64 + ub + k) ----
    float wihc[3][2][4], cbrz[2][2], cbx[2], cbh[2];
    #pragma unroll
    for (int i = 0; i < 3; ++i) {
        #pragma unroll
        for (int k = 0; k < 2; ++k) {
            const int g = i * 64 + ub + k;
            #pragma unroll
            for (int d = 0; d < 4; ++d) wihc[i][k][d] = W_ih[g * DD + d] * sc[i];
            if (i < 2) cbrz[i][k] = (b_ih[g] + b_hh[g]) * sc[i];
            else       { cbx[k] = b_ih[g] * sc[2]; cbh[k] = b_hh[g] * sc[2]; }
        }
    }

    // ---- init: zero h limb buffers (h0 = 0) ----
    for (int idx = tid; idx < 2 * SB * KP / 2; idx += 256) {
        reinterpret_cast<unsigned*>(hhi)[idx] = 0u;
        reinterpret_cast<unsigned*>(hlo)[idx] = 0u;
    }
    float hreg[2] = {0.f, 0.f};   // h[s][ub + k]

    // ---- x_0 into registers (lane's seq = n0 + s) ----
    float4 xc = *reinterpret_cast<const float4*>(
        xg + ((size_t)(b * TT) * NN + n0 + s) * DD);
    __syncthreads();

    const bool hi8b = (hi8 != 0);   // loop-invariant per-lane bool -> cndmask selects
    const f32x4 z4 = {0.f, 0.f, 0.f, 0.f};

    #pragma unroll 2
    for (int t = 0; t < TT; ++t) {
        const int cur = t & 1, nxt = cur ^ 1;
        const int tn  = (t + 1 < TT) ? t + 1 : t;

        // prefetch x_{t+1}
        float4 xn = *reinterpret_cast<const float4*>(
            xg + ((size_t)(b * TT + tn) * NN + n0 + s) * DD);

        // ---- B fragments: h limbs; row s (lanes lr>=8 broadcast-read row lr-8) ----
        bf16x8 bh0 = *reinterpret_cast<const bf16x8*>(&hhi[cur][s][lg * 8]);
        bf16x8 bh1 = *reinterpret_cast<const bf16x8*>(&hhi[cur][s][32 + lg * 8]);
        bf16x8 bl0 = *reinterpret_cast<const bf16x8*>(&hlo[cur][s][lg * 8]);
        bf16x8 bl1 = *reinterpret_cast<const bf16x8*>(&hlo[cur][s][32 + lg * 8]);

        // ---- gx for (seq s, 2 owned units): 24 FMAs ----
        float gxv[3][2];
        #pragma unroll
        for (int i = 0; i < 3; ++i) {
            #pragma unroll
            for (int k = 0; k < 2; ++k) {
                const float c0 = (i < 2) ? cbrz[i][k] : cbx[k];
                gxv[i][k] = fmaf(wihc[i][k][0], xc.x, fmaf(wihc[i][k][1], xc.y,
                            fmaf(wihc[i][k][2], xc.z, fmaf(wihc[i][k][3], xc.w, c0))));
            }
        }

        // ---- 8 MFMAs: R,Z hi-only (depth 2); N full limb correction (depth 4) ----
        f32x4 aN = __builtin_amdgcn_mfma_f32_16x16x32_bf16(awh[2][0], bl0, z4, 0,0,0);
        f32x4 aR = __builtin_amdgcn_mfma_f32_16x16x32_bf16(awh[0][0], bh0, z4, 0,0,0);
        f32x4 aZ = __builtin_amdgcn_mfma_f32_16x16x32_bf16(awh[1][0], bh0, z4, 0,0,0);
        aN = __builtin_amdgcn_mfma_f32_16x16x32_bf16(awh[2][1], bl1, aN, 0,0,0);
        aR = __builtin_amdgcn_mfma_f32_16x16x32_bf16(awh[0][1], bh1, aR, 0,0,0);
        aZ = __builtin_amdgcn_mfma_f32_16x16x32_bf16(awh[1][1], bh1, aZ, 0,0,0);
        aN = __builtin_amdgcn_mfma_f32_16x16x32_bf16(awh[2][0], bh0, aN, 0,0,0);
        aN = __builtin_amdgcn_mfma_f32_16x16x32_bf16(awh[2][1], bh1, aN, 0,0,0);

        // ---- row-pair select: 6 cndmasks (acc cols duplicate across lane halves) ----
        float vR0 = hi8b ? aR[2] : aR[0];
        float vR1 = hi8b ? aR[3] : aR[1];
        float vZ0 = hi8b ? aZ[2] : aZ[0];
        float vZ1 = hi8b ? aZ[3] : aZ[1];
        float vN0 = hi8b ? aN[2] : aN[0];
        float vN1 = hi8b ? aN[3] : aN[1];

        // ---- gates (exp2 domain) for the 2 owned rows ----
        float hn0, hn1;
        {
            float sR  = vR0 + gxv[0][0];
            float sZ  = vZ0 + gxv[1][0];
            float ghn = vN0 + cbh[0];
            float rg = __builtin_amdgcn_rcpf(1.0f + __builtin_amdgcn_exp2f(-sR));
            float ez = __builtin_amdgcn_exp2f(-sZ);
            float na = fmaf(rg, ghn, gxv[2][0]);
            float e  = __builtin_amdgcn_exp2f(-na);
            float nn = fmaf(2.0f, __builtin_amdgcn_rcpf(1.0f + e), -1.0f);  // tanh
            float z  = __builtin_amdgcn_rcpf(1.0f + ez);
            hn0 = fmaf(z, hreg[0] - nn, nn);
            hreg[0] = hn0;
        }
        {
            float sR  = vR1 + gxv[0][1];
            float sZ  = vZ1 + gxv[1][1];
            float ghn = vN1 + cbh[1];
            float rg = __builtin_amdgcn_rcpf(1.0f + __builtin_amdgcn_exp2f(-sR));
            float ez = __builtin_amdgcn_exp2f(-sZ);
            float na = fmaf(rg, ghn, gxv[2][1]);
            float e  = __builtin_amdgcn_exp2f(-na);
            float nn = fmaf(2.0f, __builtin_amdgcn_rcpf(1.0f + e), -1.0f);
            float z  = __builtin_amdgcn_rcpf(1.0f + ez);
            hn1 = fmaf(z, hreg[1] - nn, nn);
            hreg[1] = hn1;
        }

        // ---- limb split + pack via v_perm (bytes 3:2 of each float) ----
        unsigned ph = __builtin_amdgcn_perm(__float_as_uint(hn1), __float_as_uint(hn0),
                                            0x07060302u);
        float lf0 = hn0 - __uint_as_float(__float_as_uint(hn0) & 0xffff0000u);
        float lf1 = hn1 - __uint_as_float(__float_as_uint(hn1) & 0xffff0000u);
        unsigned pl = __builtin_amdgcn_perm(__float_as_uint(lf1), __float_as_uint(lf0),
                                            0x07060302u);
        *reinterpret_cast<unsigned*>(&hhi[nxt][s][ub]) = ph;   // h[s][ub..ub+1] hi
        *reinterpret_cast<unsigned*>(&hlo[nxt][s][ub]) = pl;   // lo
        xc = xn;
        __syncthreads();   // h_{t+1} limbs visible; buf[cur] free next iteration
    }

    // ---- epilogue: out = h @ W_enc^T + b_enc (256 outputs, 1 per thread) ----
    hsf[s][ub]     = hreg[0];
    hsf[s][ub + 1] = hreg[1];
    __syncthreads();
    {
        const int so = tid >> 5, li = tid & 31;
        float a = b_enc[li];
        #pragma unroll
        for (int k = 0; k < HH; ++k)
            a = fmaf(hsf[so][k], W_enc[li * HH + k], a);
        out[(bid * SB + so) * LL + li] = a;
    }
}

extern "C" void kernel_launch(void* const* d_in, const int* in_sizes, int n_in,
                              void* d_out, int out_size, void* d_ws, size_t ws_size,
                              hipStream_t stream) {
    const float* xg    = (const float*)d_in[0];
    const float* W_ih  = (const float*)d_in[1];
    const float* W_hh  = (const float*)d_in[2];
    const float* b_ih  = (const float*)d_in[3];
    const float* b_hh  = (const float*)d_in[4];
    const float* W_enc = (const float*)d_in[5];
    const float* b_enc = (const float*)d_in[6];
    float* out = (float*)d_out;

    dim3 grid(8 * BPB), block(256);   // 512 blocks -> 2 independent blocks/CU
    hipLaunchKernelGGL(gru_traj_kernel, grid, block, 0, stream,
                       xg, W_ih, W_hh, b_ih, b_hh, W_enc, b_enc, out);
}

// Round 17
// 92.090 us; speedup vs baseline: 1.3927x; 1.0333x over previous
//
#include <hip/hip_runtime.h>

#define TT 200
#define NN 512
#define DD 4
#define HH 64
#define LL 32
#define SB 8                 // sequences per block (B-cols duplicated to fill M=16)
#define BPB (NN / SB)        // 64 blocks per batch
#define KP 72                // ushort pitch per h row (144B = 9*16B)
#define LOG2E 1.44269504088896340736f

typedef short bf16x8 __attribute__((ext_vector_type(8)));
typedef float f32x4 __attribute__((ext_vector_type(4)));

union U8 { unsigned short s[8]; unsigned u[4]; bf16x8 v; };

// f32 -> hi bf16 limb by truncation
__device__ __forceinline__ unsigned short hi16(float x) {
    return (unsigned short)(__float_as_uint(x) >> 16);
}

__global__ __launch_bounds__(256, 2)
void gru_traj_kernel(const float* __restrict__ xg,    // (B,T,N,D)
                     const float* __restrict__ W_ih,  // (192,4)
                     const float* __restrict__ W_hh,  // (192,64)
                     const float* __restrict__ b_ih,  // (192,)
                     const float* __restrict__ b_hh,  // (192,)
                     const float* __restrict__ W_enc, // (32,64)
                     const float* __restrict__ b_enc, // (32,)
                     float* __restrict__ out)         // (B,N,32)
{
    __shared__ __align__(16) unsigned short hhi[2][SB][KP];   // h bf16 (dbuf)
    __shared__ __align__(16) float hsf[SB][HH + 4];           // f32 h for epilogue

    const int tid = threadIdx.x;
    const int bid = blockIdx.x;
    const int b   = bid >> 6;                // bid / BPB
    const int n0  = (bid & (BPB - 1)) * SB;  // first seq of this block

    const int w  = tid >> 6;     // wave 0..3 -> unit-group 16w..16w+15 (C rows)
    const int l  = tid & 63;
    const int lr = l & 15;       // A-row / B-col / C-col within tile
    const int lg = l >> 4;       // k-group (A/B) and C row-group
    const int s  = l & 7;        // owned seq (lanes lr and lr+8 share a seq)
    const int hi8 = (lr >> 3) & 1;           // 0: rows {0,1}; 1: rows {2,3} of acc
    const int u0 = 16 * w + lg * 4;          // first of 4 C rows in this lane's acc
    const int ub = u0 + 2 * hi8;             // first of 2 owned units (gate phase)

    const float sc[3] = { LOG2E, LOG2E, 2.0f * LOG2E };

    // ---- A statics: W_hh hi-limbs ----
    bf16x8 awh[3][2];
    #pragma unroll
    for (int i = 0; i < 3; ++i) {
        const int g = i * 64 + 16 * w + lr;
        #pragma unroll
        for (int kc = 0; kc < 2; ++kc) {
            const float* p = W_hh + g * HH + kc * 32 + lg * 8;
            U8 uh;
            #pragma unroll
            for (int j = 0; j < 8; ++j) uh.s[j] = hi16(p[j] * sc[i]);
            awh[i][kc] = uh.v;
        }
    }
    // ---- per-lane gate constants for the 2 owned units (g = i*64 + ub + k) ----
    float wihc[3][2][4], cbrz[2][2], cbx[2], cbh[2];
    #pragma unroll
    for (int i = 0; i < 3; ++i) {
        #pragma unroll
        for (int k = 0; k < 2; ++k) {
            const int g = i * 64 + ub + k;
            #pragma unroll
            for (int d = 0; d < 4; ++d) wihc[i][k][d] = W_ih[g * DD + d] * sc[i];
            if (i < 2) cbrz[i][k] = (b_ih[g] + b_hh[g]) * sc[i];
            else       { cbx[k] = b_ih[g] * sc[2]; cbh[k] = b_hh[g] * sc[2]; }
        }
    }

    // ---- init: zero h buffer (h0 = 0) ----
    for (int idx = tid; idx < 2 * SB * KP / 2; idx += 256)
        reinterpret_cast<unsigned*>(hhi)[idx] = 0u;
    float hreg[2] = {0.f, 0.f};   // h[s][ub + k] (full f32 state, never quantized)

    // ---- x_0 into registers (lane's seq = n0 + s) ----
    float4 xc = *reinterpret_cast<const float4*>(
        xg + ((size_t)(b * TT) * NN + n0 + s) * DD);
    __syncthreads();

    const bool hi8b = (hi8 != 0);   // loop-invariant per-lane bool -> cndmask selects
    const f32x4 z4 = {0.f, 0.f, 0.f, 0.f};

    #pragma unroll 2
    for (int t = 0; t < TT; ++t) {
        const int cur = t & 1, nxt = cur ^ 1;
        const int tn  = (t + 1 < TT) ? t + 1 : t;

        // prefetch x_{t+1}
        float4 xn = *reinterpret_cast<const float4*>(
            xg + ((size_t)(b * TT + tn) * NN + n0 + s) * DD);

        // ---- B fragments: h bf16; row s (lanes lr>=8 broadcast-read row lr-8) ----
        bf16x8 bh0 = *reinterpret_cast<const bf16x8*>(&hhi[cur][s][lg * 8]);
        bf16x8 bh1 = *reinterpret_cast<const bf16x8*>(&hhi[cur][s][32 + lg * 8]);

        // ---- gx for (seq s, 2 owned units): 24 FMAs ----
        float gxv[3][2];
        #pragma unroll
        for (int i = 0; i < 3; ++i) {
            #pragma unroll
            for (int k = 0; k < 2; ++k) {
                const float c0 = (i < 2) ? cbrz[i][k] : cbx[k];
                gxv[i][k] = fmaf(wihc[i][k][0], xc.x, fmaf(wihc[i][k][1], xc.y,
                            fmaf(wihc[i][k][2], xc.z, fmaf(wihc[i][k][3], xc.w, c0))));
            }
        }

        // ---- 6 MFMAs: 3 independent depth-2 chains ----
        f32x4 aR = __builtin_amdgcn_mfma_f32_16x16x32_bf16(awh[0][0], bh0, z4, 0,0,0);
        f32x4 aZ = __builtin_amdgcn_mfma_f32_16x16x32_bf16(awh[1][0], bh0, z4, 0,0,0);
        f32x4 aN = __builtin_amdgcn_mfma_f32_16x16x32_bf16(awh[2][0], bh0, z4, 0,0,0);
        aR = __builtin_amdgcn_mfma_f32_16x16x32_bf16(awh[0][1], bh1, aR, 0,0,0);
        aZ = __builtin_amdgcn_mfma_f32_16x16x32_bf16(awh[1][1], bh1, aZ, 0,0,0);
        aN = __builtin_amdgcn_mfma_f32_16x16x32_bf16(awh[2][1], bh1, aN, 0,0,0);

        // ---- row-pair select: 6 cndmasks (acc cols duplicate across lane halves) ----
        float vR0 = hi8b ? aR[2] : aR[0];
        float vR1 = hi8b ? aR[3] : aR[1];
        float vZ0 = hi8b ? aZ[2] : aZ[0];
        float vZ1 = hi8b ? aZ[3] : aZ[1];
        float vN0 = hi8b ? aN[2] : aN[0];
        float vN1 = hi8b ? aN[3] : aN[1];

        // ---- gates (exp2 domain) for the 2 owned rows ----
        float hn0, hn1;
        {
            float sR  = vR0 + gxv[0][0];
            float sZ  = vZ0 + gxv[1][0];
            float ghn = vN0 + cbh[0];
            float rg = __builtin_amdgcn_rcpf(1.0f + __builtin_amdgcn_exp2f(-sR));
            float ez = __builtin_amdgcn_exp2f(-sZ);
            float na = fmaf(rg, ghn, gxv[2][0]);
            float e  = __builtin_amdgcn_exp2f(-na);
            float nn = fmaf(2.0f, __builtin_amdgcn_rcpf(1.0f + e), -1.0f);  // tanh
            float z  = __builtin_amdgcn_rcpf(1.0f + ez);
            hn0 = fmaf(z, hreg[0] - nn, nn);
            hreg[0] = hn0;
        }
        {
            float sR  = vR1 + gxv[0][1];
            float sZ  = vZ1 + gxv[1][1];
            float ghn = vN1 + cbh[1];
            float rg = __builtin_amdgcn_rcpf(1.0f + __builtin_amdgcn_exp2f(-sR));
            float ez = __builtin_amdgcn_exp2f(-sZ);
            float na = fmaf(rg, ghn, gxv[2][1]);
            float e  = __builtin_amdgcn_exp2f(-na);
            float nn = fmaf(2.0f, __builtin_amdgcn_rcpf(1.0f + e), -1.0f);
            float z  = __builtin_amdgcn_rcpf(1.0f + ez);
            hn1 = fmaf(z, hreg[1] - nn, nn);
            hreg[1] = hn1;
        }

        // ---- bf16 pack via v_perm (bytes 3:2 of each float), 1 ds_write_b32 ----
        unsigned ph = __builtin_amdgcn_perm(__float_as_uint(hn1), __float_as_uint(hn0),
                                            0x07060302u);
        *reinterpret_cast<unsigned*>(&hhi[nxt][s][ub]) = ph;   // h[s][ub..ub+1]
        xc = xn;
        __syncthreads();   // h_{t+1} visible; buf[cur] free next iteration
    }

    // ---- epilogue: out = h @ W_enc^T + b_enc (256 outputs, 1 per thread) ----
    hsf[s][ub]     = hreg[0];
    hsf[s][ub + 1] = hreg[1];
    __syncthreads();
    {
        const int so = tid >> 5, li = tid & 31;
        float a = b_enc[li];
        #pragma unroll
        for (int k = 0; k < HH; ++k)
            a = fmaf(hsf[so][k], W_enc[li * HH + k], a);
        out[(bid * SB + so) * LL + li] = a;
    }
}

extern "C" void kernel_launch(void* const* d_in, const int* in_sizes, int n_in,
                              void* d_out, int out_size, void* d_ws, size_t ws_size,
                              hipStream_t stream) {
    const float* xg    = (const float*)d_in[0];
    const float* W_ih  = (const float*)d_in[1];
    const float* W_hh  = (const float*)d_in[2];
    const float* b_ih  = (const float*)d_in[3];
    const float* b_hh  = (const float*)d_in[4];
    const float* W_enc = (const float*)d_in[5];
    const float* b_enc = (const float*)d_in[6];
    float* out = (float*)d_out;

    dim3 grid(8 * BPB), block(256);   // 512 blocks -> 2 independent blocks/CU
    hipLaunchKernelGGL(gru_traj_kernel, grid, block, 0, stream,
                       xg, W_ih, W_hh, b_ih, b_hh, W_enc, b_enc, out);
}